// Round 2
// baseline (1073.649 us; speedup 1.0000x reference)
//
#include <hip/hip_runtime.h>
#include <stdint.h>

// GINNet on MI355X — R5: overlap the random px gather with the counting sort.
// R4 counters: k_bucket_red 346us, VALUBusy 1.4%, HBM 30%, FETCH 790 MB
// (~710 MB = random px[src] line misses). Gather (fabric time ~330us) and
// partition's LDS sort (CU time ~300us) were in separate kernels -> serial.
// R5 FAT path: partition Phase D gathers px[src] and writes 12 B/edge
// "fat" records into per-bucket planes (dst&1023 and z stolen into the low
// mantissa bits: 4+4+5, rel err <= 2^-18). The gather issues before the
// binary search per edge -> latency hides under LDS work. k_bucket_red
// becomes pure streaming (coalesced plane reads + LDS atomics).
// acc aliases each bucket's own plane region (all reads precede writeout).
// Fat path needs ~232 MB workspace; host checks ws_size and falls back to
// the byte-identical R4 path otherwise.

#define N_NODES  1000000
#define N_EDGES  16000000
#define N_GRAPHS 10000
#define NB       1024        // buckets = dst>>10 (977 used)
#define NBUCK    977
#define BCAP     18432       // per-bucket capacity (mean 16376, sigma ~128)
#define EPB      16384       // edges per partition block
#define PBLK     977         // ceil(16e6 / 16384)
#define PSTRIDE  (3 * BCAP)  // floats per bucket in fat planes (55296)
#define PS4      (PSTRIDE / 4) // float4 per bucket (13824)

__global__ __launch_bounds__(256) void k_features(
    const float* __restrict__ pos, const int* __restrict__ z,
    float4* __restrict__ px)
{
    int i = blockIdx.x * 256 + threadIdx.x;
    if (i >= N_NODES) return;
    px[i] = make_float4(pos[i * 3 + 0], pos[i * 3 + 1], pos[i * 3 + 2],
                        __int_as_float(z[i]));
}

__global__ __launch_bounds__(256) void k_init(
    const float* __restrict__ fcb, float* __restrict__ out, int* __restrict__ cursor)
{
    int i = blockIdx.x * 256 + threadIdx.x;
    if (i < N_GRAPHS) out[i] = fcb[0];
    if (i < NB) cursor[i] = 0;
}

template<int FAT>
__global__ __launch_bounds__(256) void k_partition(
    const int* __restrict__ ei, int* __restrict__ cursor,
    uint32_t* __restrict__ perm, const float4* __restrict__ px)
{
    __shared__ uint32_t sVal[EPB];   // 64 KB: bucket-sorted packed edges
    __shared__ int sHist[NB];        // counts -> exclusive prefix (lstart)
    __shared__ int sGB[NB];          // global base per bucket
    __shared__ int sCur[NB];         // scatter cursor
    __shared__ int sScan[256];

    int t = threadIdx.x;
    int e0 = blockIdx.x * EPB;
    int nE = N_EDGES - e0; if (nE > EPB) nE = EPB;

    for (int c = t; c < NB; c += 256) sHist[c] = 0;
    __syncthreads();

    const int4* src4 = (const int4*)ei;
    const int4* dst4 = (const int4*)(ei + N_EDGES);
    int i40 = e0 >> 2;

    // Phase A: histogram of dst buckets (LDS atomics)
    #pragma unroll
    for (int jj = 0; jj < EPB / 1024; jj++) {
        int i4 = i40 + jj * 256 + t;
        if (i4 * 4 < N_EDGES) {
            int4 d = dst4[i4];
            atomicAdd(&sHist[d.x >> 10], 1);
            atomicAdd(&sHist[d.y >> 10], 1);
            atomicAdd(&sHist[d.z >> 10], 1);
            atomicAdd(&sHist[d.w >> 10], 1);
        }
    }
    __syncthreads();

    // Phase B1: reserve global space (<=1024 atomics per block, not per edge)
    #pragma unroll
    for (int k = 0; k < 4; k++) {
        int c = t * 4 + k;
        int cnt = sHist[c];
        sGB[c] = cnt ? atomicAdd(&cursor[c], cnt) : 0;
    }
    // Phase B2: exclusive prefix of sHist (two-level scan)
    int pt = 0;
    #pragma unroll
    for (int k = 0; k < 4; k++) pt += sHist[t * 4 + k];
    sScan[t] = pt;
    __syncthreads();
    for (int off = 1; off < 256; off <<= 1) {
        int v = (t >= off) ? sScan[t - off] : 0;
        __syncthreads();
        sScan[t] += v;
        __syncthreads();
    }
    int base = (t == 0) ? 0 : sScan[t - 1];
    #pragma unroll
    for (int k = 0; k < 4; k++) {
        int c = t * 4 + k;
        int cnt = sHist[c];
        sHist[c] = base;      // lstart (exclusive prefix)
        sCur[c]  = base;      // running scatter cursor
        base += cnt;
    }
    __syncthreads();

    // Phase C: counting-sort scatter into LDS (returning LDS atomics only)
    #pragma unroll
    for (int jj = 0; jj < EPB / 1024; jj++) {
        int i4 = i40 + jj * 256 + t;
        if (i4 * 4 < N_EDGES) {
            int4 s = src4[i4];
            int4 d = dst4[i4];
            int b, p;
            b = d.x >> 10; p = atomicAdd(&sCur[b], 1);
            sVal[p] = ((uint32_t)s.x << 10) | (uint32_t)(d.x & 1023);
            b = d.y >> 10; p = atomicAdd(&sCur[b], 1);
            sVal[p] = ((uint32_t)s.y << 10) | (uint32_t)(d.y & 1023);
            b = d.z >> 10; p = atomicAdd(&sCur[b], 1);
            sVal[p] = ((uint32_t)s.z << 10) | (uint32_t)(d.z & 1023);
            b = d.w >> 10; p = atomicAdd(&sCur[b], 1);
            sVal[p] = ((uint32_t)s.w << 10) | (uint32_t)(d.w & 1023);
        }
    }
    __syncthreads();

    // Phase D: coalesced run writes; bucket-of-j via binary search on lstart.
    // FAT: gather px[src] here (issues before the search -> latency hides
    // under the LDS binary-search work) and write 3 plane words with
    // dst&1023 (4+4+2 bits) and z (3 bits) stolen into the low mantissa.
    #pragma unroll 2
    for (int j = t; j < nE; j += 256) {
        uint32_t v = sVal[j];
        int lo = 0;
        #pragma unroll
        for (int st = 512; st; st >>= 1) {
            int cand = lo + st;
            if (cand < NB && sHist[cand] <= j) lo = cand;
        }
        int off = j - sHist[lo];
        if (FAT) {
            float4 g = px[v >> 10];
            uint32_t d = v & 1023u;
            uint32_t zz = (uint32_t)__float_as_int(g.w) & 7u;
            size_t bofs = (size_t)lo * PSTRIDE + (size_t)(sGB[lo] + off);
            perm[bofs]            = (__float_as_uint(g.x) & ~15u) | (d & 15u);
            perm[bofs + BCAP]     = (__float_as_uint(g.y) & ~15u) | ((d >> 4) & 15u);
            perm[bofs + 2 * BCAP] = (__float_as_uint(g.z) & ~31u) | ((d >> 8) & 3u)
                                  | (zz << 2);
        } else {
            perm[(size_t)lo * BCAP + sGB[lo] + off] = v;
        }
    }
}

// ---------- classic (R4) reduction: random gather in this kernel ----------
__global__ __launch_bounds__(512) void k_bucket_red(
    const uint32_t* __restrict__ perm, const int* __restrict__ cursor,
    const float4* __restrict__ px, const float* __restrict__ emb,
    float* __restrict__ acc)
{
    __shared__ float sAcc[1024 * 9];  // 36.9 KB: 3 pos sums + 5 z counts
    __shared__ float sEmb[25];
    int t = threadIdx.x;
    int b = blockIdx.x;

    for (int j = t; j < 1024 * 9; j += 512) sAcc[j] = 0.0f;
    if (t < 25) sEmb[t] = emb[t];
    __syncthreads();

    int n = cursor[b];
    if (n > BCAP) n = BCAP;
    const uint32_t* pb = perm + (size_t)b * BCAP;

    #pragma unroll 4
    for (int j = t; j < n; j += 512) {
        uint32_t p = pb[j];
        float4 g = px[p >> 10];
        float* s = sAcc + (p & 1023u) * 9;
        atomicAdd(s + 0, g.x);
        atomicAdd(s + 1, g.y);
        atomicAdd(s + 2, g.z);
        atomicAdd(s + 3 + __float_as_int(g.w), 1.0f);
    }
    __syncthreads();

    for (int q = t; q < 1024; q += 512) {
        int node = (b << 10) + q;
        if (node >= N_NODES) continue;
        float4 me = px[node];
        int mz = __float_as_int(me.w);
        const float* s = sAcc + q * 9;
        float c0 = s[3], c1 = s[4], c2 = s[5], c3 = s[6], c4 = s[7];
        float e[5];
        #pragma unroll
        for (int c = 0; c < 5; c++) {
            e[c] = sEmb[mz * 5 + c]
                 + c0 * sEmb[0 * 5 + c] + c1 * sEmb[1 * 5 + c]
                 + c2 * sEmb[2 * 5 + c] + c3 * sEmb[3 * 5 + c]
                 + c4 * sEmb[4 * 5 + c];
        }
        float4* av = (float4*)acc;
        av[(size_t)node * 2 + 0] = make_float4(me.x + s[0], me.y + s[1],
                                               me.z + s[2], e[0]);
        av[(size_t)node * 2 + 1] = make_float4(e[1], e[2], e[3], e[4]);
    }
}

// ---------- fat reduction: pure streaming, acc aliases own plane region ----
__global__ __launch_bounds__(512) void k_bucket_red_f(
    uint32_t* __restrict__ planes, const int* __restrict__ cursor,
    const float4* __restrict__ px, const float* __restrict__ emb)
{
    __shared__ float sAcc[1024 * 9];
    __shared__ float sEmb[25];
    int t = threadIdx.x;
    int b = blockIdx.x;

    for (int j = t; j < 1024 * 9; j += 512) sAcc[j] = 0.0f;
    if (t < 25) sEmb[t] = emb[t];
    __syncthreads();

    int n = cursor[b];
    if (n > BCAP) n = BCAP;
    uint32_t* pb = planes + (size_t)b * PSTRIDE;

    #pragma unroll 2
    for (int j = t; j < n; j += 512) {
        uint32_t wx = pb[j];
        uint32_t wy = pb[j + BCAP];
        uint32_t wz = pb[j + 2 * BCAP];
        uint32_t d  = (wx & 15u) | ((wy & 15u) << 4) | ((wz & 3u) << 8);
        uint32_t zz = (wz >> 2) & 7u;
        float* s = sAcc + d * 9;
        atomicAdd(s + 0, __uint_as_float(wx));
        atomicAdd(s + 1, __uint_as_float(wy));
        atomicAdd(s + 2, __uint_as_float(wz));
        atomicAdd(s + 3 + zz, 1.0f);
    }
    __syncthreads();

    // writeout into THIS bucket's plane region (all reads are done)
    float4* av = (float4*)pb;
    for (int q = t; q < 1024; q += 512) {
        int node = (b << 10) + q;
        if (node >= N_NODES) continue;
        float4 me = px[node];
        int mz = __float_as_int(me.w);
        const float* s = sAcc + q * 9;
        float c0 = s[3], c1 = s[4], c2 = s[5], c3 = s[6], c4 = s[7];
        float e[5];
        #pragma unroll
        for (int c = 0; c < 5; c++) {
            e[c] = sEmb[mz * 5 + c]
                 + c0 * sEmb[0 * 5 + c] + c1 * sEmb[1 * 5 + c]
                 + c2 * sEmb[2 * 5 + c] + c3 * sEmb[3 * 5 + c]
                 + c4 * sEmb[4 * 5 + c];
        }
        av[q * 2 + 0] = make_float4(me.x + s[0], me.y + s[1], me.z + s[2], e[0]);
        av[q * 2 + 1] = make_float4(e[1], e[2], e[3], e[4]);
    }
}

template<int FAT>
__global__ __launch_bounds__(256) void k_mlp_pool(
    const float* __restrict__ acc, const int* __restrict__ batch,
    const float* __restrict__ W1, const float* __restrict__ b1,
    const float* __restrict__ W2, const float* __restrict__ b2,
    const float* __restrict__ fcW, float* __restrict__ out)
{
    __shared__ float sW1[512];    // [8][64]
    __shared__ float sW2[4096];   // [64][64]
    __shared__ float sB1[64], sB2[64], sFc[64];
    __shared__ float redS[256];
    __shared__ int   redG[256];

    int t = threadIdx.x;
    for (int j = t; j < 512; j += 256)  sW1[j] = W1[j];
    for (int j = t; j < 4096; j += 256) sW2[j] = W2[j];
    if (t < 64) { sB1[t] = b1[t]; sB2[t] = b2[t]; sFc[t] = fcW[t]; }
    __syncthreads();

    int i = blockIdx.x * 256 + t;
    float s = 0.0f;
    int g = -1;
    if (i < N_NODES) {
        const float4* av = (const float4*)acc;
        size_t a0 = FAT ? ((size_t)(i >> 10) * PS4 + (size_t)(i & 1023) * 2)
                        : ((size_t)i * 2);
        float4 u0 = av[a0 + 0];
        float4 u1 = av[a0 + 1];
        float f[8] = {u0.x, u0.y, u0.z, u0.w, u1.x, u1.y, u1.z, u1.w};

        const float4* w1v = (const float4*)sW1;
        const float4* w2v = (const float4*)sW2;
        const float4* b1v = (const float4*)sB1;
        const float4* b2v = (const float4*)sB2;
        const float4* fcv = (const float4*)sFc;

        float h1[64];
        #pragma unroll
        for (int o = 0; o < 16; o++) {
            float4 a4 = b1v[o];
            #pragma unroll
            for (int k = 0; k < 8; k++) {
                float4 w = w1v[k * 16 + o];
                a4.x = fmaf(f[k], w.x, a4.x);
                a4.y = fmaf(f[k], w.y, a4.y);
                a4.z = fmaf(f[k], w.z, a4.z);
                a4.w = fmaf(f[k], w.w, a4.w);
            }
            h1[o * 4 + 0] = fmaxf(a4.x, 0.0f);
            h1[o * 4 + 1] = fmaxf(a4.y, 0.0f);
            h1[o * 4 + 2] = fmaxf(a4.z, 0.0f);
            h1[o * 4 + 3] = fmaxf(a4.w, 0.0f);
        }
        for (int o = 0; o < 16; o++) {
            float4 a4 = b2v[o];
            #pragma unroll
            for (int k = 0; k < 64; k++) {
                float4 w = w2v[k * 16 + o];
                a4.x = fmaf(h1[k], w.x, a4.x);
                a4.y = fmaf(h1[k], w.y, a4.y);
                a4.z = fmaf(h1[k], w.z, a4.z);
                a4.w = fmaf(h1[k], w.w, a4.w);
            }
            float4 fc = fcv[o];
            s += fmaxf(a4.x, 0.0f) * fc.x;
            s += fmaxf(a4.y, 0.0f) * fc.y;
            s += fmaxf(a4.z, 0.0f) * fc.z;
            s += fmaxf(a4.w, 0.0f) * fc.w;
        }
        g = batch[i];
    }

    redS[t] = s;
    redG[t] = g;
    __syncthreads();
    if (g >= 0 && (t == 0 || redG[t - 1] != g)) {
        float sum = s;
        for (int j = t + 1; j < 256 && redG[j] == g; j++) sum += redS[j];
        unsafeAtomicAdd(&out[g], sum);
    }
}

extern "C" void kernel_launch(void* const* d_in, const int* in_sizes, int n_in,
                              void* d_out, int out_size, void* d_ws, size_t ws_size,
                              hipStream_t stream) {
    const float* pos  = (const float*)d_in[0];
    const int*   z    = (const int*)  d_in[1];
    const int*   ei   = (const int*)  d_in[2];
    const int*   batch= (const int*)  d_in[3];
    const float* emb  = (const float*)d_in[4];
    const float* W1   = (const float*)d_in[5];
    const float* b1   = (const float*)d_in[6];
    const float* W2   = (const float*)d_in[7];
    const float* b2   = (const float*)d_in[8];
    const float* fcW  = (const float*)d_in[9];
    const float* fcb  = (const float*)d_in[10];
    float* out = (float*)d_out;

    // fat layout:   px 16 MB | cursor 4 KB | planes 216.2 MB  (~232 MB)
    // classic (R4): px 16 MB | perm 75.5 MB | cursor | acc 32 MB (~124 MB)
    size_t planesB  = (size_t)NBUCK * PSTRIDE * 4;
    size_t fatNeed  = (size_t)N_NODES * 16 + 4096 + planesB;

    float4* px     = (float4*)d_ws;

    if (ws_size >= fatNeed) {
        int*      cursor = (int*)((char*)d_ws + (size_t)N_NODES * 16);
        uint32_t* planes = (uint32_t*)((char*)d_ws + (size_t)N_NODES * 16 + 4096);

        k_features    <<<(N_NODES + 255) / 256, 256, 0, stream>>>(pos, z, px);
        k_init        <<<(N_GRAPHS + 255) / 256, 256, 0, stream>>>(fcb, out, cursor);
        k_partition<1><<<PBLK, 256, 0, stream>>>(ei, cursor, planes, px);
        k_bucket_red_f<<<NBUCK, 512, 0, stream>>>(planes, cursor, px, emb);
        k_mlp_pool<1> <<<(N_NODES + 255) / 256, 256, 0, stream>>>(
            (const float*)planes, batch, W1, b1, W2, b2, fcW, out);
    } else {
        uint32_t* perm   = (uint32_t*)((float*)d_ws + (size_t)N_NODES * 4);
        int*      cursor = (int*)(perm + (size_t)NB * BCAP);
        float*    acc    = (float*)(cursor + NB);

        k_features    <<<(N_NODES + 255) / 256, 256, 0, stream>>>(pos, z, px);
        k_init        <<<(N_GRAPHS + 255) / 256, 256, 0, stream>>>(fcb, out, cursor);
        k_partition<0><<<PBLK, 256, 0, stream>>>(ei, cursor, perm, px);
        k_bucket_red  <<<NBUCK, 512, 0, stream>>>(perm, cursor, px, emb, acc);
        k_mlp_pool<0> <<<(N_NODES + 255) / 256, 256, 0, stream>>>(
            acc, batch, W1, b1, W2, b2, fcW, out);
    }
}

// Round 3
// 933.214 us; speedup vs baseline: 1.1505x; 1.1505x over previous
//
#include <hip/hip_runtime.h>
#include <stdint.h>

// GINNet on MI355X — R6: revert R5 fat path (regressed 849->1074: gather moved
// into a 2-block/CU kernel, occupancy 21%, FETCH unchanged). R4 skeleton plus:
//  * k_partition: EPB 16384->8192 -> LDS 78.8->45.3 KB -> 3 blocks/CU
//    (12 waves, +50% latency hiding for the LDS-sort phases). PBLK=1954.
//  * k_bucket_red: explicit 6-deep miss pipeline (6 perm reads -> 6 px
//    gathers in flight -> 24 LDS atomics) instead of unroll-4.
//  * k_mlp_pool: 2 nodes/thread -> each broadcast ds_read_b128 of W1/W2
//    feeds 8 FMAs (was 4); per-node DS instruction count halves.
//
//  k_features   : px[i] = {pos | bitcast(z)}
//  k_init       : out[g] = fcb[0]; cursor[b] = 0
//  k_partition  : block-local counting sort of edges by dst>>10 into perm
//  k_bucket_red : per bucket: LDS {pos-sum,z-count} over 1024 nodes, then
//                 acc = [pos+possum | emb[z]+cnt@emb]
//  k_mlp_pool   : s_i = relu(relu(acc@W1+b1)@W2+b2).fcW, segmented block
//                 reduce over sorted batch -> atomicAdd(out[g])

#define N_NODES  1000000
#define N_EDGES  16000000
#define N_GRAPHS 10000
#define NB       1024        // buckets = dst>>10 (977 used)
#define NBUCK    977
#define BCAP     18432       // per-bucket capacity (mean 16376, sigma ~128)
#define EPB      8192        // edges per partition block (R6: halved)
#define PBLK     1954        // ceil(16e6 / 8192)

__global__ __launch_bounds__(256) void k_features(
    const float* __restrict__ pos, const int* __restrict__ z,
    float4* __restrict__ px)
{
    int i = blockIdx.x * 256 + threadIdx.x;
    if (i >= N_NODES) return;
    px[i] = make_float4(pos[i * 3 + 0], pos[i * 3 + 1], pos[i * 3 + 2],
                        __int_as_float(z[i]));
}

__global__ __launch_bounds__(256) void k_init(
    const float* __restrict__ fcb, float* __restrict__ out, int* __restrict__ cursor)
{
    int i = blockIdx.x * 256 + threadIdx.x;
    if (i < N_GRAPHS) out[i] = fcb[0];
    if (i < NB) cursor[i] = 0;
}

__global__ __launch_bounds__(256) void k_partition(
    const int* __restrict__ ei, int* __restrict__ cursor, uint32_t* __restrict__ perm)
{
    __shared__ uint32_t sVal[EPB];   // 32 KB: bucket-sorted packed edges
    __shared__ int sHist[NB];        // counts -> exclusive prefix (lstart)
    __shared__ int sGB[NB];          // global base per bucket
    __shared__ int sCur[NB];         // scatter cursor
    __shared__ int sScan[256];

    int t = threadIdx.x;
    int e0 = blockIdx.x * EPB;
    int nE = N_EDGES - e0; if (nE > EPB) nE = EPB;

    for (int c = t; c < NB; c += 256) sHist[c] = 0;
    __syncthreads();

    const int4* src4 = (const int4*)ei;
    const int4* dst4 = (const int4*)(ei + N_EDGES);
    int i40 = e0 >> 2;

    // Phase A: histogram of dst buckets (LDS atomics)
    #pragma unroll
    for (int jj = 0; jj < EPB / 1024; jj++) {
        int i4 = i40 + jj * 256 + t;
        if (i4 * 4 < N_EDGES) {
            int4 d = dst4[i4];
            atomicAdd(&sHist[d.x >> 10], 1);
            atomicAdd(&sHist[d.y >> 10], 1);
            atomicAdd(&sHist[d.z >> 10], 1);
            atomicAdd(&sHist[d.w >> 10], 1);
        }
    }
    __syncthreads();

    // Phase B1: reserve global space (<=1024 atomics per block, not per edge)
    #pragma unroll
    for (int k = 0; k < 4; k++) {
        int c = t * 4 + k;
        int cnt = sHist[c];
        sGB[c] = cnt ? atomicAdd(&cursor[c], cnt) : 0;
    }
    // Phase B2: exclusive prefix of sHist (two-level scan)
    int pt = 0;
    #pragma unroll
    for (int k = 0; k < 4; k++) pt += sHist[t * 4 + k];
    sScan[t] = pt;
    __syncthreads();
    for (int off = 1; off < 256; off <<= 1) {
        int v = (t >= off) ? sScan[t - off] : 0;
        __syncthreads();
        sScan[t] += v;
        __syncthreads();
    }
    int base = (t == 0) ? 0 : sScan[t - 1];
    #pragma unroll
    for (int k = 0; k < 4; k++) {
        int c = t * 4 + k;
        int cnt = sHist[c];
        sHist[c] = base;      // lstart (exclusive prefix)
        sCur[c]  = base;      // running scatter cursor
        base += cnt;
    }
    __syncthreads();

    // Phase C: counting-sort scatter into LDS (returning LDS atomics only)
    #pragma unroll
    for (int jj = 0; jj < EPB / 1024; jj++) {
        int i4 = i40 + jj * 256 + t;
        if (i4 * 4 < N_EDGES) {
            int4 s = src4[i4];
            int4 d = dst4[i4];
            int b, p;
            b = d.x >> 10; p = atomicAdd(&sCur[b], 1);
            sVal[p] = ((uint32_t)s.x << 10) | (uint32_t)(d.x & 1023);
            b = d.y >> 10; p = atomicAdd(&sCur[b], 1);
            sVal[p] = ((uint32_t)s.y << 10) | (uint32_t)(d.y & 1023);
            b = d.z >> 10; p = atomicAdd(&sCur[b], 1);
            sVal[p] = ((uint32_t)s.z << 10) | (uint32_t)(d.z & 1023);
            b = d.w >> 10; p = atomicAdd(&sCur[b], 1);
            sVal[p] = ((uint32_t)s.w << 10) | (uint32_t)(d.w & 1023);
        }
    }
    __syncthreads();

    // Phase D: coalesced run writes; bucket-of-j via binary search on lstart
    for (int j = t; j < nE; j += 256) {
        uint32_t v = sVal[j];
        int lo = 0;
        #pragma unroll
        for (int st = 512; st; st >>= 1) {
            int cand = lo + st;
            if (cand < NB && sHist[cand] <= j) lo = cand;
        }
        int off = j - sHist[lo];
        perm[(size_t)lo * BCAP + sGB[lo] + off] = v;
    }
}

__global__ __launch_bounds__(512) void k_bucket_red(
    const uint32_t* __restrict__ perm, const int* __restrict__ cursor,
    const float4* __restrict__ px, const float* __restrict__ emb,
    float* __restrict__ acc)
{
    __shared__ float sAcc[1024 * 9];  // 36.9 KB: 3 pos sums + 5 z counts
    __shared__ float sEmb[25];
    int t = threadIdx.x;
    int b = blockIdx.x;

    for (int j = t; j < 1024 * 9; j += 512) sAcc[j] = 0.0f;
    if (t < 25) sEmb[t] = emb[t];
    __syncthreads();

    int n = cursor[b];
    if (n > BCAP) n = BCAP;            // unreachable (~16 sigma), safety only
    const uint32_t* pb = perm + (size_t)b * BCAP;

    // 6-deep miss pipeline: 6 perm reads -> 6 px gathers in flight -> atomics
    const uint32_t SENT = 0xFFFFFFFFu;
    for (int base = 0; base < n; base += 512 * 6) {
        uint32_t pv[6];
        #pragma unroll
        for (int k = 0; k < 6; k++) {
            int jj = base + t + k * 512;
            pv[k] = (jj < n) ? pb[jj] : SENT;
        }
        float4 g[6];
        #pragma unroll
        for (int k = 0; k < 6; k++) {
            if (pv[k] != SENT) g[k] = px[pv[k] >> 10];
        }
        #pragma unroll
        for (int k = 0; k < 6; k++) {
            if (pv[k] == SENT) continue;
            float* s = sAcc + (pv[k] & 1023u) * 9;
            atomicAdd(s + 0, g[k].x);
            atomicAdd(s + 1, g[k].y);
            atomicAdd(s + 2, g[k].z);
            atomicAdd(s + 3 + __float_as_int(g[k].w), 1.0f);
        }
    }
    __syncthreads();

    // writeout: acc[node] = [pos + possum | emb[z] + cnt @ emb]
    for (int q = t; q < 1024; q += 512) {
        int node = (b << 10) + q;
        if (node >= N_NODES) continue;
        float4 me = px[node];
        int mz = __float_as_int(me.w);
        const float* s = sAcc + q * 9;
        float c0 = s[3], c1 = s[4], c2 = s[5], c3 = s[6], c4 = s[7];
        float e[5];
        #pragma unroll
        for (int c = 0; c < 5; c++) {
            e[c] = sEmb[mz * 5 + c]
                 + c0 * sEmb[0 * 5 + c] + c1 * sEmb[1 * 5 + c]
                 + c2 * sEmb[2 * 5 + c] + c3 * sEmb[3 * 5 + c]
                 + c4 * sEmb[4 * 5 + c];
        }
        float4* av = (float4*)acc;
        av[(size_t)node * 2 + 0] = make_float4(me.x + s[0], me.y + s[1],
                                               me.z + s[2], e[0]);
        av[(size_t)node * 2 + 1] = make_float4(e[1], e[2], e[3], e[4]);
    }
}

// 2 nodes per thread: block covers 512 nodes; each broadcast weight read
// feeds 8 FMAs (was 4) -> per-node DS instruction count halves.
__global__ __launch_bounds__(256) void k_mlp_pool(
    const float* __restrict__ acc, const int* __restrict__ batch,
    const float* __restrict__ W1, const float* __restrict__ b1,
    const float* __restrict__ W2, const float* __restrict__ b2,
    const float* __restrict__ fcW, float* __restrict__ out)
{
    __shared__ float sW1[512];    // [8][64]
    __shared__ float sW2[4096];   // [64][64]
    __shared__ float sB1[64], sB2[64], sFc[64];
    __shared__ float redS[512];
    __shared__ int   redG[512];

    int t = threadIdx.x;
    for (int j = t; j < 512; j += 256)  sW1[j] = W1[j];
    for (int j = t; j < 4096; j += 256) sW2[j] = W2[j];
    if (t < 64) { sB1[t] = b1[t]; sB2[t] = b2[t]; sFc[t] = fcW[t]; }
    __syncthreads();

    int i0 = blockIdx.x * 512 + t;
    int i1 = i0 + 256;
    float s0 = 0.0f, s1 = 0.0f;
    int g0 = -1, g1 = -1;
    bool a0 = (i0 < N_NODES), a1 = (i1 < N_NODES);

    const float4* av  = (const float4*)acc;
    const float4* w1v = (const float4*)sW1;
    const float4* w2v = (const float4*)sW2;
    const float4* b1v = (const float4*)sB1;
    const float4* b2v = (const float4*)sB2;
    const float4* fcv = (const float4*)sFc;

    float fA[8] = {0,0,0,0,0,0,0,0}, fB[8] = {0,0,0,0,0,0,0,0};
    if (a0) {
        float4 u0 = av[(size_t)i0 * 2 + 0];
        float4 u1 = av[(size_t)i0 * 2 + 1];
        fA[0]=u0.x; fA[1]=u0.y; fA[2]=u0.z; fA[3]=u0.w;
        fA[4]=u1.x; fA[5]=u1.y; fA[6]=u1.z; fA[7]=u1.w;
        g0 = batch[i0];
    }
    if (a1) {
        float4 u0 = av[(size_t)i1 * 2 + 0];
        float4 u1 = av[(size_t)i1 * 2 + 1];
        fB[0]=u0.x; fB[1]=u0.y; fB[2]=u0.z; fB[3]=u0.w;
        fB[4]=u1.x; fB[5]=u1.y; fB[6]=u1.z; fB[7]=u1.w;
        g1 = batch[i1];
    }

    float h1a[64], h1b[64];
    #pragma unroll
    for (int o = 0; o < 16; o++) {
        float4 aA = b1v[o], aB = aA;
        #pragma unroll
        for (int k = 0; k < 8; k++) {
            float4 w = w1v[k * 16 + o];
            aA.x = fmaf(fA[k], w.x, aA.x);  aB.x = fmaf(fB[k], w.x, aB.x);
            aA.y = fmaf(fA[k], w.y, aA.y);  aB.y = fmaf(fB[k], w.y, aB.y);
            aA.z = fmaf(fA[k], w.z, aA.z);  aB.z = fmaf(fB[k], w.z, aB.z);
            aA.w = fmaf(fA[k], w.w, aA.w);  aB.w = fmaf(fB[k], w.w, aB.w);
        }
        h1a[o*4+0] = fmaxf(aA.x, 0.0f);  h1b[o*4+0] = fmaxf(aB.x, 0.0f);
        h1a[o*4+1] = fmaxf(aA.y, 0.0f);  h1b[o*4+1] = fmaxf(aB.y, 0.0f);
        h1a[o*4+2] = fmaxf(aA.z, 0.0f);  h1b[o*4+2] = fmaxf(aB.z, 0.0f);
        h1a[o*4+3] = fmaxf(aA.w, 0.0f);  h1b[o*4+3] = fmaxf(aB.w, 0.0f);
    }
    for (int o = 0; o < 16; o++) {
        float4 aA = b2v[o], aB = aA;
        #pragma unroll
        for (int k = 0; k < 64; k++) {
            float4 w = w2v[k * 16 + o];
            aA.x = fmaf(h1a[k], w.x, aA.x);  aB.x = fmaf(h1b[k], w.x, aB.x);
            aA.y = fmaf(h1a[k], w.y, aA.y);  aB.y = fmaf(h1b[k], w.y, aB.y);
            aA.z = fmaf(h1a[k], w.z, aA.z);  aB.z = fmaf(h1b[k], w.z, aB.z);
            aA.w = fmaf(h1a[k], w.w, aA.w);  aB.w = fmaf(h1b[k], w.w, aB.w);
        }
        float4 fc = fcv[o];
        s0 += fmaxf(aA.x, 0.0f) * fc.x + fmaxf(aA.y, 0.0f) * fc.y
            + fmaxf(aA.z, 0.0f) * fc.z + fmaxf(aA.w, 0.0f) * fc.w;
        s1 += fmaxf(aB.x, 0.0f) * fc.x + fmaxf(aB.y, 0.0f) * fc.y
            + fmaxf(aB.z, 0.0f) * fc.z + fmaxf(aB.w, 0.0f) * fc.w;
    }

    redS[t] = s0;       redG[t] = a0 ? g0 : -1;
    redS[t + 256] = s1; redG[t + 256] = a1 ? g1 : -1;
    __syncthreads();
    #pragma unroll
    for (int w = 0; w < 2; w++) {
        int idx = t + w * 256;
        int g = redG[idx];
        if (g >= 0 && (idx == 0 || redG[idx - 1] != g)) {
            float sum = redS[idx];
            for (int j = idx + 1; j < 512 && redG[j] == g; j++) sum += redS[j];
            unsafeAtomicAdd(&out[g], sum);
        }
    }
}

extern "C" void kernel_launch(void* const* d_in, const int* in_sizes, int n_in,
                              void* d_out, int out_size, void* d_ws, size_t ws_size,
                              hipStream_t stream) {
    const float* pos  = (const float*)d_in[0];
    const int*   z    = (const int*)  d_in[1];
    const int*   ei   = (const int*)  d_in[2];
    const int*   batch= (const int*)  d_in[3];
    const float* emb  = (const float*)d_in[4];
    const float* W1   = (const float*)d_in[5];
    const float* b1   = (const float*)d_in[6];
    const float* W2   = (const float*)d_in[7];
    const float* b2   = (const float*)d_in[8];
    const float* fcW  = (const float*)d_in[9];
    const float* fcb  = (const float*)d_in[10];
    float* out = (float*)d_out;

    // workspace layout (16B-aligned): px 16 MB | perm 75.5 MB | cursor | acc 32 MB
    float4*   px     = (float4*)d_ws;
    uint32_t* perm   = (uint32_t*)((float*)d_ws + (size_t)N_NODES * 4);
    int*      cursor = (int*)(perm + (size_t)NB * BCAP);
    float*    acc    = (float*)(cursor + NB);

    k_features <<<(N_NODES + 255) / 256, 256, 0, stream>>>(pos, z, px);
    k_init     <<<(N_GRAPHS + 255) / 256, 256, 0, stream>>>(fcb, out, cursor);
    k_partition<<<PBLK, 256, 0, stream>>>(ei, cursor, perm);
    k_bucket_red<<<NBUCK, 512, 0, stream>>>(perm, cursor, px, emb, acc);
    k_mlp_pool <<<(N_NODES + 511) / 512, 256, 0, stream>>>(acc, batch,
                                                           W1, b1, W2, b2, fcW, out);
}

// Round 4
// 843.326 us; speedup vs baseline: 1.2731x; 1.1066x over previous
//
#include <hip/hip_runtime.h>
#include <stdint.h>

// GINNet on MI355X — R7: revert R6 (all three changes regressed; 933 vs 849),
// back to the R4 skeleton, then ONE structural change: fuse MLP+pool into the
// bucket kernel so the MLP's VALU/DS work executes inside the gather's
// latency shadow (gather phase runs at VALUBusy 1.4% — CUs idle on L3 line
// service; 4 staggered blocks/CU provide the overlap).
// Occupancy is protected (R5 lesson):
//  * sAcc packed 9->5 words/node (3 pos floats + u32 of five 6-bit z-counts
//    + pad; stride 5 coprime with 32 banks). LDS total 39.8 KB -> 4 blk/CU.
//  * MLP recomputes h1 per 16-wide output chunk (live set ~50 VGPR);
//    __launch_bounds__(512,8) pins the 64-VGPR tier for the gather phase.
//  * acc[] round-trip (64 MB) and k_mlp_pool deleted.
//
//  k_features   : px[i] = {pos | bitcast(z)}
//  k_init       : out[g] = fcb[0]; cursor[b] = 0
//  k_partition  : block-local counting sort of edges by dst>>10 into perm
//                 (byte-identical to R4: EPB=16384, PBLK=977)
//  k_bucket_mlp : per bucket: LDS {pos-sum,z-count} gather, then per-node
//                 MLP + segmented pooled reduce -> atomicAdd(out[g])

#define N_NODES  1000000
#define N_EDGES  16000000
#define N_GRAPHS 10000
#define NB       1024        // buckets = dst>>10 (977 used)
#define NBUCK    977
#define BCAP     18432       // per-bucket capacity (mean 16376, sigma ~128)
#define EPB      16384       // edges per partition block
#define PBLK     977         // ceil(16e6 / 16384)

__global__ __launch_bounds__(256) void k_features(
    const float* __restrict__ pos, const int* __restrict__ z,
    float4* __restrict__ px)
{
    int i = blockIdx.x * 256 + threadIdx.x;
    if (i >= N_NODES) return;
    px[i] = make_float4(pos[i * 3 + 0], pos[i * 3 + 1], pos[i * 3 + 2],
                        __int_as_float(z[i]));
}

__global__ __launch_bounds__(256) void k_init(
    const float* __restrict__ fcb, float* __restrict__ out, int* __restrict__ cursor)
{
    int i = blockIdx.x * 256 + threadIdx.x;
    if (i < N_GRAPHS) out[i] = fcb[0];
    if (i < NB) cursor[i] = 0;
}

__global__ __launch_bounds__(256) void k_partition(
    const int* __restrict__ ei, int* __restrict__ cursor, uint32_t* __restrict__ perm)
{
    __shared__ uint32_t sVal[EPB];   // 64 KB: bucket-sorted packed edges
    __shared__ int sHist[NB];        // counts -> exclusive prefix (lstart)
    __shared__ int sGB[NB];          // global base per bucket
    __shared__ int sCur[NB];         // scatter cursor
    __shared__ int sScan[256];

    int t = threadIdx.x;
    int e0 = blockIdx.x * EPB;
    int nE = N_EDGES - e0; if (nE > EPB) nE = EPB;

    for (int c = t; c < NB; c += 256) sHist[c] = 0;
    __syncthreads();

    const int4* src4 = (const int4*)ei;
    const int4* dst4 = (const int4*)(ei + N_EDGES);
    int i40 = e0 >> 2;

    // Phase A: histogram of dst buckets (LDS atomics)
    #pragma unroll
    for (int jj = 0; jj < EPB / 1024; jj++) {
        int i4 = i40 + jj * 256 + t;
        if (i4 * 4 < N_EDGES) {
            int4 d = dst4[i4];
            atomicAdd(&sHist[d.x >> 10], 1);
            atomicAdd(&sHist[d.y >> 10], 1);
            atomicAdd(&sHist[d.z >> 10], 1);
            atomicAdd(&sHist[d.w >> 10], 1);
        }
    }
    __syncthreads();

    // Phase B1: reserve global space (<=1024 atomics per block, not per edge)
    #pragma unroll
    for (int k = 0; k < 4; k++) {
        int c = t * 4 + k;
        int cnt = sHist[c];
        sGB[c] = cnt ? atomicAdd(&cursor[c], cnt) : 0;
    }
    // Phase B2: exclusive prefix of sHist (two-level scan)
    int pt = 0;
    #pragma unroll
    for (int k = 0; k < 4; k++) pt += sHist[t * 4 + k];
    sScan[t] = pt;
    __syncthreads();
    for (int off = 1; off < 256; off <<= 1) {
        int v = (t >= off) ? sScan[t - off] : 0;
        __syncthreads();
        sScan[t] += v;
        __syncthreads();
    }
    int base = (t == 0) ? 0 : sScan[t - 1];
    #pragma unroll
    for (int k = 0; k < 4; k++) {
        int c = t * 4 + k;
        int cnt = sHist[c];
        sHist[c] = base;      // lstart (exclusive prefix)
        sCur[c]  = base;      // running scatter cursor
        base += cnt;
    }
    __syncthreads();

    // Phase C: counting-sort scatter into LDS (returning LDS atomics only)
    #pragma unroll
    for (int jj = 0; jj < EPB / 1024; jj++) {
        int i4 = i40 + jj * 256 + t;
        if (i4 * 4 < N_EDGES) {
            int4 s = src4[i4];
            int4 d = dst4[i4];
            int b, p;
            b = d.x >> 10; p = atomicAdd(&sCur[b], 1);
            sVal[p] = ((uint32_t)s.x << 10) | (uint32_t)(d.x & 1023);
            b = d.y >> 10; p = atomicAdd(&sCur[b], 1);
            sVal[p] = ((uint32_t)s.y << 10) | (uint32_t)(d.y & 1023);
            b = d.z >> 10; p = atomicAdd(&sCur[b], 1);
            sVal[p] = ((uint32_t)s.z << 10) | (uint32_t)(d.z & 1023);
            b = d.w >> 10; p = atomicAdd(&sCur[b], 1);
            sVal[p] = ((uint32_t)s.w << 10) | (uint32_t)(d.w & 1023);
        }
    }
    __syncthreads();

    // Phase D: coalesced run writes; bucket-of-j via binary search on lstart
    for (int j = t; j < nE; j += 256) {
        uint32_t v = sVal[j];
        int lo = 0;
        #pragma unroll
        for (int st = 512; st; st >>= 1) {
            int cand = lo + st;
            if (cand < NB && sHist[cand] <= j) lo = cand;
        }
        int off = j - sHist[lo];
        perm[(size_t)lo * BCAP + sGB[lo] + off] = v;
    }
}

// Fused: gather-reduce into packed LDS, then per-node MLP + pooled reduce.
__global__ __launch_bounds__(512, 8) void k_bucket_mlp(
    const uint32_t* __restrict__ perm, const int* __restrict__ cursor,
    const float4* __restrict__ px, const float* __restrict__ emb,
    const int* __restrict__ batch,
    const float* __restrict__ W1, const float* __restrict__ b1,
    const float* __restrict__ W2, const float* __restrict__ b2,
    const float* __restrict__ fcW, float* __restrict__ out)
{
    __shared__ float sAcc[1024 * 5];  // 20.5 KB: pos x3 | packed counts | pad
    __shared__ float sW1T[512];       // [64][8]  (transposed W1)
    __shared__ float sW2[4096];       // [64][64]
    __shared__ float sB1[64], sB2[64], sFc[64];
    __shared__ float sEmb[25];

    int t = threadIdx.x;
    int b = blockIdx.x;

    for (int j = t; j < 1024 * 5; j += 512) sAcc[j] = 0.0f;
    {   // W1 [8][64] -> sW1T [64][8]
        int j = t >> 6, k = t & 63;       // t in [0,512)
        sW1T[k * 8 + j] = W1[j * 64 + k];
    }
    for (int j = t; j < 4096; j += 512) sW2[j] = W2[j];
    if (t < 64) { sB1[t] = b1[t]; sB2[t] = b2[t]; sFc[t] = fcW[t]; }
    if (t < 25) sEmb[t] = emb[t];
    __syncthreads();

    int n = cursor[b];
    if (n > BCAP) n = BCAP;            // unreachable (~16 sigma), safety only
    const uint32_t* pb = perm + (size_t)b * BCAP;

    // gather phase (R4-proven form): 3 float adds + 1 packed-count add
    #pragma unroll 4
    for (int j = t; j < n; j += 512) {
        uint32_t p = pb[j];
        float4 g = px[p >> 10];
        float* s = sAcc + (p & 1023u) * 5;
        atomicAdd(s + 0, g.x);
        atomicAdd(s + 1, g.y);
        atomicAdd(s + 2, g.z);
        atomicAdd((unsigned int*)(s + 3), 1u << (6 * __float_as_int(g.w)));
    }
    __syncthreads();

    // per-node MLP (2 sequential nodes/thread; h1 recomputed per 16-chunk)
    float sv[2]; int gv[2];
    #pragma unroll
    for (int half = 0; half < 2; half++) {
        int q = t + half * 512;
        int node = (b << 10) + q;
        float s = 0.0f; int g = -1;
        if (node < N_NODES) {
            float4 me = px[node];
            int mz = __float_as_int(me.w);
            const float* sa = sAcc + q * 5;
            unsigned int pk = *(const unsigned int*)(sa + 3);
            float f[8];
            f[0] = me.x + sa[0]; f[1] = me.y + sa[1]; f[2] = me.z + sa[2];
            float c0 = (float)(pk & 63u);
            float c1 = (float)((pk >> 6) & 63u);
            float c2 = (float)((pk >> 12) & 63u);
            float c3 = (float)((pk >> 18) & 63u);
            float c4 = (float)((pk >> 24) & 63u);
            #pragma unroll
            for (int e = 0; e < 5; e++) {
                f[3 + e] = sEmb[mz * 5 + e]
                         + c0 * sEmb[e]      + c1 * sEmb[5 + e]
                         + c2 * sEmb[10 + e] + c3 * sEmb[15 + e]
                         + c4 * sEmb[20 + e];
            }
            const float4* w1t = (const float4*)sW1T;
            const float4* w2v = (const float4*)sW2;
            #pragma unroll
            for (int oc = 0; oc < 4; oc++) {
                float a[16];
                #pragma unroll
                for (int i2 = 0; i2 < 16; i2++) a[i2] = sB2[oc * 16 + i2];
                for (int k = 0; k < 64; k++) {
                    float4 wa = w1t[k * 2 + 0];
                    float4 wb = w1t[k * 2 + 1];
                    float h = sB1[k];
                    h = fmaf(f[0], wa.x, h); h = fmaf(f[1], wa.y, h);
                    h = fmaf(f[2], wa.z, h); h = fmaf(f[3], wa.w, h);
                    h = fmaf(f[4], wb.x, h); h = fmaf(f[5], wb.y, h);
                    h = fmaf(f[6], wb.z, h); h = fmaf(f[7], wb.w, h);
                    h = fmaxf(h, 0.0f);
                    #pragma unroll
                    for (int v4 = 0; v4 < 4; v4++) {
                        float4 w = w2v[k * 16 + oc * 4 + v4];
                        a[v4*4+0] = fmaf(h, w.x, a[v4*4+0]);
                        a[v4*4+1] = fmaf(h, w.y, a[v4*4+1]);
                        a[v4*4+2] = fmaf(h, w.z, a[v4*4+2]);
                        a[v4*4+3] = fmaf(h, w.w, a[v4*4+3]);
                    }
                }
                #pragma unroll
                for (int i2 = 0; i2 < 16; i2++)
                    s += fmaxf(a[i2], 0.0f) * sFc[oc * 16 + i2];
            }
            g = batch[node];
        }
        sv[half] = s; gv[half] = g;
    }
    __syncthreads();   // all sAcc reads done -> safe to alias

    float* redS = sAcc;                 // [1024]
    int*   redG = (int*)(sAcc + 1024);  // [1024]
    redS[t]       = sv[0];  redG[t]       = gv[0];
    redS[t + 512] = sv[1];  redG[t + 512] = gv[1];
    __syncthreads();
    #pragma unroll
    for (int w = 0; w < 2; w++) {
        int idx = t + w * 512;
        int g = redG[idx];
        if (g >= 0 && (idx == 0 || redG[idx - 1] != g)) {
            float sum = redS[idx];
            for (int j = idx + 1; j < 1024 && redG[j] == g; j++) sum += redS[j];
            unsafeAtomicAdd(&out[g], sum);
        }
    }
}

extern "C" void kernel_launch(void* const* d_in, const int* in_sizes, int n_in,
                              void* d_out, int out_size, void* d_ws, size_t ws_size,
                              hipStream_t stream) {
    const float* pos  = (const float*)d_in[0];
    const int*   z    = (const int*)  d_in[1];
    const int*   ei   = (const int*)  d_in[2];
    const int*   batch= (const int*)  d_in[3];
    const float* emb  = (const float*)d_in[4];
    const float* W1   = (const float*)d_in[5];
    const float* b1   = (const float*)d_in[6];
    const float* W2   = (const float*)d_in[7];
    const float* b2   = (const float*)d_in[8];
    const float* fcW  = (const float*)d_in[9];
    const float* fcb  = (const float*)d_in[10];
    float* out = (float*)d_out;

    // workspace layout (16B-aligned): px 16 MB | perm 75.5 MB | cursor
    float4*   px     = (float4*)d_ws;
    uint32_t* perm   = (uint32_t*)((float*)d_ws + (size_t)N_NODES * 4);
    int*      cursor = (int*)(perm + (size_t)NB * BCAP);

    k_features <<<(N_NODES + 255) / 256, 256, 0, stream>>>(pos, z, px);
    k_init     <<<(N_GRAPHS + 255) / 256, 256, 0, stream>>>(fcb, out, cursor);
    k_partition<<<PBLK, 256, 0, stream>>>(ei, cursor, perm);
    k_bucket_mlp<<<NBUCK, 512, 0, stream>>>(perm, cursor, px, emb, batch,
                                            W1, b1, W2, b2, fcW, out);
}

// Round 5
// 833.942 us; speedup vs baseline: 1.2874x; 1.0113x over previous
//
#include <hip/hip_runtime.h>
#include <stdint.h>

// GINNet on MI355X — R8: fix R7's scratch spill. R7 counters: VGPR_Count=32
// (launch_bounds(512,8) forced a 32-VGPR fit), WRITE_SIZE=508 MB of spill
// stores + ~270 MB spill re-reads in FETCH. The fused gather+MLP concept
// works (HBM 2.9 TB/s and VALU 27% co-scheduled); the pragma overshot.
// Single change: __launch_bounds__(512,8) -> (512,6): VGPR cap 64->80
// (MLP live set ~50-65: a[16]+f[8]+wa/wb+pipelining), 3 blocks/CU
// (24 waves) kept for gather latency hiding. Everything else identical.
//
//  k_features   : px[i] = {pos | bitcast(z)}
//  k_init       : out[g] = fcb[0]; cursor[b] = 0
//  k_partition  : block-local counting sort of edges by dst>>10 into perm
//                 (byte-identical to R4: EPB=16384, PBLK=977)
//  k_bucket_mlp : per bucket: LDS {pos-sum,z-count} gather, then per-node
//                 MLP + segmented pooled reduce -> atomicAdd(out[g])

#define N_NODES  1000000
#define N_EDGES  16000000
#define N_GRAPHS 10000
#define NB       1024        // buckets = dst>>10 (977 used)
#define NBUCK    977
#define BCAP     18432       // per-bucket capacity (mean 16376, sigma ~128)
#define EPB      16384       // edges per partition block
#define PBLK     977         // ceil(16e6 / 16384)

__global__ __launch_bounds__(256) void k_features(
    const float* __restrict__ pos, const int* __restrict__ z,
    float4* __restrict__ px)
{
    int i = blockIdx.x * 256 + threadIdx.x;
    if (i >= N_NODES) return;
    px[i] = make_float4(pos[i * 3 + 0], pos[i * 3 + 1], pos[i * 3 + 2],
                        __int_as_float(z[i]));
}

__global__ __launch_bounds__(256) void k_init(
    const float* __restrict__ fcb, float* __restrict__ out, int* __restrict__ cursor)
{
    int i = blockIdx.x * 256 + threadIdx.x;
    if (i < N_GRAPHS) out[i] = fcb[0];
    if (i < NB) cursor[i] = 0;
}

__global__ __launch_bounds__(256) void k_partition(
    const int* __restrict__ ei, int* __restrict__ cursor, uint32_t* __restrict__ perm)
{
    __shared__ uint32_t sVal[EPB];   // 64 KB: bucket-sorted packed edges
    __shared__ int sHist[NB];        // counts -> exclusive prefix (lstart)
    __shared__ int sGB[NB];          // global base per bucket
    __shared__ int sCur[NB];         // scatter cursor
    __shared__ int sScan[256];

    int t = threadIdx.x;
    int e0 = blockIdx.x * EPB;
    int nE = N_EDGES - e0; if (nE > EPB) nE = EPB;

    for (int c = t; c < NB; c += 256) sHist[c] = 0;
    __syncthreads();

    const int4* src4 = (const int4*)ei;
    const int4* dst4 = (const int4*)(ei + N_EDGES);
    int i40 = e0 >> 2;

    // Phase A: histogram of dst buckets (LDS atomics)
    #pragma unroll
    for (int jj = 0; jj < EPB / 1024; jj++) {
        int i4 = i40 + jj * 256 + t;
        if (i4 * 4 < N_EDGES) {
            int4 d = dst4[i4];
            atomicAdd(&sHist[d.x >> 10], 1);
            atomicAdd(&sHist[d.y >> 10], 1);
            atomicAdd(&sHist[d.z >> 10], 1);
            atomicAdd(&sHist[d.w >> 10], 1);
        }
    }
    __syncthreads();

    // Phase B1: reserve global space (<=1024 atomics per block, not per edge)
    #pragma unroll
    for (int k = 0; k < 4; k++) {
        int c = t * 4 + k;
        int cnt = sHist[c];
        sGB[c] = cnt ? atomicAdd(&cursor[c], cnt) : 0;
    }
    // Phase B2: exclusive prefix of sHist (two-level scan)
    int pt = 0;
    #pragma unroll
    for (int k = 0; k < 4; k++) pt += sHist[t * 4 + k];
    sScan[t] = pt;
    __syncthreads();
    for (int off = 1; off < 256; off <<= 1) {
        int v = (t >= off) ? sScan[t - off] : 0;
        __syncthreads();
        sScan[t] += v;
        __syncthreads();
    }
    int base = (t == 0) ? 0 : sScan[t - 1];
    #pragma unroll
    for (int k = 0; k < 4; k++) {
        int c = t * 4 + k;
        int cnt = sHist[c];
        sHist[c] = base;      // lstart (exclusive prefix)
        sCur[c]  = base;      // running scatter cursor
        base += cnt;
    }
    __syncthreads();

    // Phase C: counting-sort scatter into LDS (returning LDS atomics only)
    #pragma unroll
    for (int jj = 0; jj < EPB / 1024; jj++) {
        int i4 = i40 + jj * 256 + t;
        if (i4 * 4 < N_EDGES) {
            int4 s = src4[i4];
            int4 d = dst4[i4];
            int b, p;
            b = d.x >> 10; p = atomicAdd(&sCur[b], 1);
            sVal[p] = ((uint32_t)s.x << 10) | (uint32_t)(d.x & 1023);
            b = d.y >> 10; p = atomicAdd(&sCur[b], 1);
            sVal[p] = ((uint32_t)s.y << 10) | (uint32_t)(d.y & 1023);
            b = d.z >> 10; p = atomicAdd(&sCur[b], 1);
            sVal[p] = ((uint32_t)s.z << 10) | (uint32_t)(d.z & 1023);
            b = d.w >> 10; p = atomicAdd(&sCur[b], 1);
            sVal[p] = ((uint32_t)s.w << 10) | (uint32_t)(d.w & 1023);
        }
    }
    __syncthreads();

    // Phase D: coalesced run writes; bucket-of-j via binary search on lstart
    for (int j = t; j < nE; j += 256) {
        uint32_t v = sVal[j];
        int lo = 0;
        #pragma unroll
        for (int st = 512; st; st >>= 1) {
            int cand = lo + st;
            if (cand < NB && sHist[cand] <= j) lo = cand;
        }
        int off = j - sHist[lo];
        perm[(size_t)lo * BCAP + sGB[lo] + off] = v;
    }
}

// Fused: gather-reduce into packed LDS, then per-node MLP + pooled reduce.
__global__ __launch_bounds__(512, 6) void k_bucket_mlp(
    const uint32_t* __restrict__ perm, const int* __restrict__ cursor,
    const float4* __restrict__ px, const float* __restrict__ emb,
    const int* __restrict__ batch,
    const float* __restrict__ W1, const float* __restrict__ b1,
    const float* __restrict__ W2, const float* __restrict__ b2,
    const float* __restrict__ fcW, float* __restrict__ out)
{
    __shared__ float sAcc[1024 * 5];  // 20.5 KB: pos x3 | packed counts | pad
    __shared__ float sW1T[512];       // [64][8]  (transposed W1)
    __shared__ float sW2[4096];       // [64][64]
    __shared__ float sB1[64], sB2[64], sFc[64];
    __shared__ float sEmb[25];

    int t = threadIdx.x;
    int b = blockIdx.x;

    for (int j = t; j < 1024 * 5; j += 512) sAcc[j] = 0.0f;
    {   // W1 [8][64] -> sW1T [64][8]
        int j = t >> 6, k = t & 63;       // t in [0,512)
        sW1T[k * 8 + j] = W1[j * 64 + k];
    }
    for (int j = t; j < 4096; j += 512) sW2[j] = W2[j];
    if (t < 64) { sB1[t] = b1[t]; sB2[t] = b2[t]; sFc[t] = fcW[t]; }
    if (t < 25) sEmb[t] = emb[t];
    __syncthreads();

    int n = cursor[b];
    if (n > BCAP) n = BCAP;            // unreachable (~16 sigma), safety only
    const uint32_t* pb = perm + (size_t)b * BCAP;

    // gather phase (R4-proven form): 3 float adds + 1 packed-count add
    #pragma unroll 4
    for (int j = t; j < n; j += 512) {
        uint32_t p = pb[j];
        float4 g = px[p >> 10];
        float* s = sAcc + (p & 1023u) * 5;
        atomicAdd(s + 0, g.x);
        atomicAdd(s + 1, g.y);
        atomicAdd(s + 2, g.z);
        atomicAdd((unsigned int*)(s + 3), 1u << (6 * __float_as_int(g.w)));
    }
    __syncthreads();

    // per-node MLP (2 sequential nodes/thread; h1 recomputed per 16-chunk)
    float sv[2]; int gv[2];
    #pragma unroll
    for (int half = 0; half < 2; half++) {
        int q = t + half * 512;
        int node = (b << 10) + q;
        float s = 0.0f; int g = -1;
        if (node < N_NODES) {
            float4 me = px[node];
            int mz = __float_as_int(me.w);
            const float* sa = sAcc + q * 5;
            unsigned int pk = *(const unsigned int*)(sa + 3);
            float f[8];
            f[0] = me.x + sa[0]; f[1] = me.y + sa[1]; f[2] = me.z + sa[2];
            float c0 = (float)(pk & 63u);
            float c1 = (float)((pk >> 6) & 63u);
            float c2 = (float)((pk >> 12) & 63u);
            float c3 = (float)((pk >> 18) & 63u);
            float c4 = (float)((pk >> 24) & 63u);
            #pragma unroll
            for (int e = 0; e < 5; e++) {
                f[3 + e] = sEmb[mz * 5 + e]
                         + c0 * sEmb[e]      + c1 * sEmb[5 + e]
                         + c2 * sEmb[10 + e] + c3 * sEmb[15 + e]
                         + c4 * sEmb[20 + e];
            }
            const float4* w1t = (const float4*)sW1T;
            const float4* w2v = (const float4*)sW2;
            #pragma unroll
            for (int oc = 0; oc < 4; oc++) {
                float a[16];
                #pragma unroll
                for (int i2 = 0; i2 < 16; i2++) a[i2] = sB2[oc * 16 + i2];
                for (int k = 0; k < 64; k++) {
                    float4 wa = w1t[k * 2 + 0];
                    float4 wb = w1t[k * 2 + 1];
                    float h = sB1[k];
                    h = fmaf(f[0], wa.x, h); h = fmaf(f[1], wa.y, h);
                    h = fmaf(f[2], wa.z, h); h = fmaf(f[3], wa.w, h);
                    h = fmaf(f[4], wb.x, h); h = fmaf(f[5], wb.y, h);
                    h = fmaf(f[6], wb.z, h); h = fmaf(f[7], wb.w, h);
                    h = fmaxf(h, 0.0f);
                    #pragma unroll
                    for (int v4 = 0; v4 < 4; v4++) {
                        float4 w = w2v[k * 16 + oc * 4 + v4];
                        a[v4*4+0] = fmaf(h, w.x, a[v4*4+0]);
                        a[v4*4+1] = fmaf(h, w.y, a[v4*4+1]);
                        a[v4*4+2] = fmaf(h, w.z, a[v4*4+2]);
                        a[v4*4+3] = fmaf(h, w.w, a[v4*4+3]);
                    }
                }
                #pragma unroll
                for (int i2 = 0; i2 < 16; i2++)
                    s += fmaxf(a[i2], 0.0f) * sFc[oc * 16 + i2];
            }
            g = batch[node];
        }
        sv[half] = s; gv[half] = g;
    }
    __syncthreads();   // all sAcc reads done -> safe to alias

    float* redS = sAcc;                 // [1024]
    int*   redG = (int*)(sAcc + 1024);  // [1024]
    redS[t]       = sv[0];  redG[t]       = gv[0];
    redS[t + 512] = sv[1];  redG[t + 512] = gv[1];
    __syncthreads();
    #pragma unroll
    for (int w = 0; w < 2; w++) {
        int idx = t + w * 512;
        int g = redG[idx];
        if (g >= 0 && (idx == 0 || redG[idx - 1] != g)) {
            float sum = redS[idx];
            for (int j = idx + 1; j < 1024 && redG[j] == g; j++) sum += redS[j];
            unsafeAtomicAdd(&out[g], sum);
        }
    }
}

extern "C" void kernel_launch(void* const* d_in, const int* in_sizes, int n_in,
                              void* d_out, int out_size, void* d_ws, size_t ws_size,
                              hipStream_t stream) {
    const float* pos  = (const float*)d_in[0];
    const int*   z    = (const int*)  d_in[1];
    const int*   ei   = (const int*)  d_in[2];
    const int*   batch= (const int*)  d_in[3];
    const float* emb  = (const float*)d_in[4];
    const float* W1   = (const float*)d_in[5];
    const float* b1   = (const float*)d_in[6];
    const float* W2   = (const float*)d_in[7];
    const float* b2   = (const float*)d_in[8];
    const float* fcW  = (const float*)d_in[9];
    const float* fcb  = (const float*)d_in[10];
    float* out = (float*)d_out;

    // workspace layout (16B-aligned): px 16 MB | perm 75.5 MB | cursor
    float4*   px     = (float4*)d_ws;
    uint32_t* perm   = (uint32_t*)((float*)d_ws + (size_t)N_NODES * 4);
    int*      cursor = (int*)(perm + (size_t)NB * BCAP);

    k_features <<<(N_NODES + 255) / 256, 256, 0, stream>>>(pos, z, px);
    k_init     <<<(N_GRAPHS + 255) / 256, 256, 0, stream>>>(fcb, out, cursor);
    k_partition<<<PBLK, 256, 0, stream>>>(ei, cursor, perm);
    k_bucket_mlp<<<NBUCK, 512, 0, stream>>>(perm, cursor, px, emb, batch,
                                            W1, b1, W2, b2, fcW, out);
}